// Round 5
// baseline (72.317 us; speedup 1.0000x reference)
//
#include <hip/hip_runtime.h>

#define B_ 64
#define N_ 900
#define C_ 16
#define NCHAR_ 75
#define L_ 8

typedef float f32x4 __attribute__((ext_vector_type(4)));

// Fused kernel, R0 geometry: 900 blocks x 64 threads, thread = one bn, ALL
// lanes active on the string stream (32B/lane/char, 2KB contiguous per wave).
// A 64-thread block spans at most 2 images; wave-level segmented min via
// shfl_xor on packed (orderable_cost<<32 | n) u64, then per-image atomicMin
// + arrival counter; last-arriving block writes out[b].
// ws: packed u64[64] @0, counters u32[64] @512; both 0xFF-filled per launch
// (packed = u64max; counter = 0xFFFFFFFF, last arrival sees old == cnt-2).
__global__ __launch_bounds__(64) void fused_kernel(
    const float* __restrict__ logits,   // [B,N,C]
    const float* __restrict__ boxes,    // [B,N,8]
    const float* __restrict__ ps,       // [B,NCHAR,N,L]
    const float* __restrict__ tgt,      // [B,4]
    const int*   __restrict__ ptype,    // [B]
    const int*   __restrict__ lps,      // [B,L]
    unsigned long long* __restrict__ packed,  // ws
    unsigned*           __restrict__ counter, // ws+512
    int* __restrict__ out)              // [B,1]
{
    int bn = blockIdx.x * 64 + threadIdx.x;   // 900*64 = 57600 exact
    int b  = bn / N_;
    int n  = bn - b * N_;

    // ---------- string CE: lse over 75 chars per l, minus target logit ----------
    int tl[L_];
    {
        const int4* lp4 = (const int4*)(lps + b * L_);
        int4 q0 = lp4[0], q1 = lp4[1];
        tl[0]=q0.x; tl[1]=q0.y; tl[2]=q0.z; tl[3]=q0.w;
        tl[4]=q1.x; tl[5]=q1.y; tl[6]=q1.z; tl[7]=q1.w;
    }
    float s[L_], tv[L_];
    #pragma unroll
    for (int l = 0; l < L_; ++l) { s[l] = 0.0f; tv[l] = 0.0f; }

    const float* base = ps + ((size_t)b * NCHAR_ * N_ + n) * L_;
    #pragma unroll 5
    for (int c = 0; c < NCHAR_; ++c) {
        const f32x4* p4 = (const f32x4*)(base + (size_t)c * (N_ * L_));
        f32x4 a = __builtin_nontemporal_load(p4);
        f32x4 d = __builtin_nontemporal_load(p4 + 1);
        s[0] += __expf(a.x); tv[0] = (c == tl[0]) ? a.x : tv[0];
        s[1] += __expf(a.y); tv[1] = (c == tl[1]) ? a.y : tv[1];
        s[2] += __expf(a.z); tv[2] = (c == tl[2]) ? a.z : tv[2];
        s[3] += __expf(a.w); tv[3] = (c == tl[3]) ? a.w : tv[3];
        s[4] += __expf(d.x); tv[4] = (c == tl[4]) ? d.x : tv[4];
        s[5] += __expf(d.y); tv[5] = (c == tl[5]) ? d.y : tv[5];
        s[6] += __expf(d.z); tv[6] = (c == tl[6]) ? d.z : tv[6];
        s[7] += __expf(d.w); tv[7] = (c == tl[7]) ? d.w : tv[7];
    }
    float ce = 0.0f;
    #pragma unroll
    for (int l = 0; l < L_; ++l) ce += __logf(s[l]) - tv[l];
    float cost_string = ce * (1.0f / L_);

    // ---------- class cost: -softmax(logits)[plate_type] ----------
    float x[C_];
    {
        const float4* lg = (const float4*)(logits + (size_t)bn * C_);
        float4 q0 = lg[0], q1 = lg[1], q2 = lg[2], q3 = lg[3];
        x[0]=q0.x; x[1]=q0.y; x[2]=q0.z; x[3]=q0.w;
        x[4]=q1.x; x[5]=q1.y; x[6]=q1.z; x[7]=q1.w;
        x[8]=q2.x; x[9]=q2.y; x[10]=q2.z; x[11]=q2.w;
        x[12]=q3.x; x[13]=q3.y; x[14]=q3.z; x[15]=q3.w;
    }
    int tcls = ptype[b];
    float m = x[0];
    #pragma unroll
    for (int i = 1; i < C_; ++i) m = fmaxf(m, x[i]);
    float se = 0.0f, xt = 0.0f;
    #pragma unroll
    for (int i = 0; i < C_; ++i) {
        se += __expf(x[i] - m);
        xt = (i == tcls) ? x[i] : xt;
    }
    float cost_class = -__expf(xt - m) / se;

    // ---------- bbox: vertices -> xyxy, L1, GIoU ----------
    float4 tb = *(const float4*)(tgt + b * 4);
    const float4* bx = (const float4*)(boxes + (size_t)bn * 8);
    float4 w0 = bx[0], w1 = bx[1];
    float px1 = fminf(fminf(w0.x, w0.z), fminf(w1.x, w1.z));
    float py1 = fminf(fminf(w0.y, w0.w), fminf(w1.y, w1.w));
    float px2 = fmaxf(fmaxf(w0.x, w0.z), fmaxf(w1.x, w1.z));
    float py2 = fmaxf(fmaxf(w0.y, w0.w), fmaxf(w1.y, w1.w));

    float cost_bbox = fabsf(px1 - tb.x) + fabsf(py1 - tb.y)
                    + fabsf(px2 - tb.z) + fabsf(py2 - tb.w);

    float ltx = fmaxf(px1, tb.x), lty = fmaxf(py1, tb.y);
    float rbx = fminf(px2, tb.z), rby = fminf(py2, tb.w);
    float iw = fmaxf(rbx - ltx, 0.0f), ih = fmaxf(rby - lty, 0.0f);
    float inter = iw * ih;
    float area_p = (px2 - px1) * (py2 - py1);
    float area_t = (tb.z - tb.x) * (tb.w - tb.y);
    float uni = area_p + area_t - inter;
    float iou = inter / uni;
    float cx1 = fminf(px1, tb.x), cy1 = fminf(py1, tb.y);
    float cx2 = fmaxf(px2, tb.z), cy2 = fmaxf(py2, tb.w);
    float cw = fmaxf(cx2 - cx1, 0.0f), ch = fmaxf(cy2 - cy1, 0.0f);
    float area_c = cw * ch;
    float giou = iou - (area_c - uni) / area_c;

    float cost = cost_class + 5.0f * cost_bbox - 2.0f * giou + 10.0f * cost_string;

    // ---------- packed (orderable cost << 32) | n : min == argmin, first-idx ----------
    unsigned u = __float_as_uint(cost);
    u = (u & 0x80000000u) ? ~u : (u | 0x80000000u);
    unsigned long long pk = ((unsigned long long)u << 32) | (unsigned)n;

    // ---------- wave segmented min (block may span 2 images) ----------
    int b0 = (blockIdx.x * 64) / N_;
    int b1 = (blockIdx.x * 64 + 63) / N_;
    unsigned long long p0 = (b == b0) ? pk : ~0ull;
    unsigned long long p1 = (b != b0) ? pk : ~0ull;
    #pragma unroll
    for (int off = 1; off < 64; off <<= 1) {
        unsigned long long q0 = __shfl_xor(p0, off);
        unsigned long long q1 = __shfl_xor(p1, off);
        p0 = (q0 < p0) ? q0 : p0;
        p1 = (q1 < p1) ? q1 : p1;
    }

    if (threadIdx.x == 0) {
        atomicMin(&packed[b0], p0);
        if (b1 != b0) atomicMin(&packed[b1], p1);
        __threadfence();
        {
            unsigned cnt = (unsigned)((N_ * b0 + N_ - 1) / 64 - (N_ * b0) / 64 + 1);
            unsigned old = atomicAdd(&counter[b0], 1u);
            if (old == cnt - 2u) {
                __threadfence();
                unsigned long long v = atomicAdd(&packed[b0], 0ull);
                out[b0] = (int)(v & 0xFFFFFFFFull);
            }
        }
        if (b1 != b0) {
            unsigned cnt = (unsigned)((N_ * b1 + N_ - 1) / 64 - (N_ * b1) / 64 + 1);
            unsigned old = atomicAdd(&counter[b1], 1u);
            if (old == cnt - 2u) {
                __threadfence();
                unsigned long long v = atomicAdd(&packed[b1], 0ull);
                out[b1] = (int)(v & 0xFFFFFFFFull);
            }
        }
    }
}

extern "C" void kernel_launch(void* const* d_in, const int* in_sizes, int n_in,
                              void* d_out, int out_size, void* d_ws, size_t ws_size,
                              hipStream_t stream) {
    const float* logits = (const float*)d_in[0];   // pred_logits [B,N,C]
    const float* boxes  = (const float*)d_in[1];   // pred_boxes  [B,N,8]
    const float* ps     = (const float*)d_in[2];   // pred_string_logits [B,75,N,8]
    const float* tgt    = (const float*)d_in[3];   // tgt_bboxes [B,4]
    const int*   ptype  = (const int*)d_in[4];     // plate_type [B]
    const int*   lps    = (const int*)d_in[5];     // lps [B,L]

    unsigned long long* packed  = (unsigned long long*)d_ws;          // 64 * 8B
    unsigned*           counter = (unsigned*)((char*)d_ws + 512);     // 64 * 4B
    int* out = (int*)d_out;

    // init: packed = u64max, counter = 0xFFFFFFFF (last arrival sees cnt-2)
    hipMemsetAsync(d_ws, 0xFF, 768, stream);

    fused_kernel<<<N_, 64, 0, stream>>>(
        logits, boxes, ps, tgt, ptype, lps, packed, counter, out);
}